// Round 3
// baseline (226.401 us; speedup 1.0000x reference)
//
#include <hip/hip_runtime.h>
#include <cstdint>

namespace {
constexpr int LROW   = 8192;
constexpr int KWIN   = 25;
constexpr int HALF   = (KWIN - 1) / 2;    // 12
constexpr int PERIOD = 24;
constexpr int NOCC   = 342;               // (L + 16) / 24 occurrences per phase
constexpr int NTHR   = 256;
constexpr int GRP    = LROW / (4 * NTHR); // 8 float4-groups per thread
constexpr int RPB    = 16;                // rows per block (pipelined)
}

__device__ __forceinline__ void ce(float& x, float& y) {
    float lo = fminf(x, y), hi = fmaxf(x, y);
    x = lo; y = hi;
}

// exact median of 5 via 9-CE sorting network
__device__ __forceinline__ float median5(float a, float b, float c, float d, float e) {
    ce(a, b); ce(d, e); ce(c, e); ce(c, d); ce(a, d); ce(a, c);
    ce(b, e); ce(b, d); ce(b, c);
    return c;
}

// async DMA stage of one 8192-float row into LDS: 8 x global_load_lds(16B)/thread.
// LDS layout is linear & lane-consecutive (16B/lane), matching the DMA's
// wave-uniform-base + lane*16 destination rule.
__device__ __forceinline__ void stage_row(const float* __restrict__ xr,
                                          float* ldsbuf, int t) {
    #pragma unroll
    for (int j = 0; j < GRP; ++j) {
        int g = 4 * (t + NTHR * j);
        __builtin_amdgcn_global_load_lds(
            (const __attribute__((address_space(1))) uint32_t*)(xr + g),
            (__attribute__((address_space(3))) uint32_t*)(ldsbuf + g),
            16, 0, 0);
    }
}

// grid = rows/RPB = 512 blocks; 2 blocks/CU (LDS-bound: 64KB dbuf + scratch).
// Row schedule: block b handles rows b, b+512, b+1024, ... so the concurrent
// working set of all blocks is a dense moving window per stream.
__global__ __launch_bounds__(NTHR, 2) void decomp_kernel(
    const float* __restrict__ x,
    float* __restrict__ out_res,
    float* __restrict__ out_trend,
    float* __restrict__ out_seas)
{
    __shared__ __align__(16) float buf[2][LROW];   // 64 KiB double buffer
    __shared__ float part[240];
    __shared__ float seasonal[PERIOD];

    const int t = threadIdx.x;
    const int b = blockIdx.x;
    const int rstride = gridDim.x;   // 512

    auto row_base = [&](int i) -> size_t {
        return ((size_t)(b + i * rstride)) * (size_t)LROW;
    };

    // prologue: fill both pipeline slots
    stage_row(x + row_base(0), buf[0], t);
    stage_row(x + row_base(1), buf[1], t);
    __syncthreads();

    for (int i = 0; i < RPB; ++i) {
        const int cur = i & 1;
        const size_t base = row_base(i);
        float* xs = buf[cur];

        // ---- trend (K=25 moving average); residuals kept in registers ----
        float resv[GRP][4];
        #pragma unroll
        for (int j = 0; j < GRP; ++j) {
            int g = 4 * (t + NTHR * j);
            float v[28];
            if (g >= HALF && g <= LROW - 16) {
                #pragma unroll
                for (int q = 0; q < 7; ++q) {
                    float4 f = *reinterpret_cast<const float4*>(xs + g - HALF + 4 * q);
                    v[4*q+0] = f.x; v[4*q+1] = f.y; v[4*q+2] = f.z; v[4*q+3] = f.w;
                }
            } else {
                // 3 threads at each row end: substitute median-of-5 pad
                float med = (g < HALF)
                    ? median5(xs[0], xs[1], xs[2], xs[3], xs[4])
                    : median5(xs[LROW-5], xs[LROW-4], xs[LROW-3], xs[LROW-2], xs[LROW-1]);
                #pragma unroll
                for (int q = 0; q < 28; ++q) {
                    int idx = g - HALF + q;
                    v[q] = (idx < 0 || idx >= LROW) ? med : xs[idx];
                }
            }
            float s = 0.f;
            #pragma unroll
            for (int q = 0; q < KWIN; ++q) s += v[q];
            constexpr float inv = 1.0f / (float)KWIN;
            float w1 = s  - v[0] + v[25];
            float w2 = w1 - v[1] + v[26];
            float w3 = w2 - v[2] + v[27];
            float t0 = s * inv, t1 = w1 * inv, t2 = w2 * inv, t3 = w3 * inv;
            resv[j][0] = v[12] - t0;
            resv[j][1] = v[13] - t1;
            resv[j][2] = v[14] - t2;
            resv[j][3] = v[15] - t3;
            *reinterpret_cast<float4*>(out_trend + base + g) =
                make_float4(t0, t1, t2, t3);
        }
        __syncthreads();   // A: all window reads done before in-place overwrite

        // ---- residual -> xs (each thread overwrites only its own slots) ----
        #pragma unroll
        for (int j = 0; j < GRP; ++j) {
            int g = 4 * (t + NTHR * j);
            *reinterpret_cast<float4*>(xs + g) =
                make_float4(resv[j][0], resv[j][1], resv[j][2], resv[j][3]);
        }
        __syncthreads();   // B: res visible to gather

        // ---- per-phase partial sums: 24 phases x 10 threads ----
        // seasonal[p] = (1/342) * sum_k xpad[24k+p];
        // xpad[m] = res[m] for m<8192 else res[m-24] (reference's dup pad)
        if (t < 240) {
            const int p = t / 10, s0 = t % 10;
            float acc = 0.f;
            for (int k = s0; k < NOCC; k += 10) {
                int m = PERIOD * k + p;
                if (m >= LROW) m -= PERIOD;
                acc += xs[m];
            }
            part[t] = acc;   // separate scratch: no WAR barrier needed
        }
        __syncthreads();   // C: partials visible; buf[cur] is now dead

        // buf[cur] dead -> issue DMA for row i+2 under the remaining phases
        // (drained by the next row's barriers long before use at row i+2)
        if (i + 2 < RPB) stage_row(x + row_base(i + 2), buf[cur], t);

        if (t < PERIOD) {
            float s = 0.f;
            #pragma unroll
            for (int q = 0; q < 10; ++q) s += part[t * 10 + q];
            seasonal[t] = s / (float)NOCC;
        }
        __syncthreads();   // D: seasonal visible

        // ---- outputs: residual - seasonal, tiled seasonal ----
        #pragma unroll
        for (int j = 0; j < GRP; ++j) {
            int g = 4 * (t + NTHR * j);
            int ph = g % PERIOD;   // multiple of 4, <= 20, so ph+3 never wraps
            float s0 = seasonal[ph + 0];
            float s1 = seasonal[ph + 1];
            float s2 = seasonal[ph + 2];
            float s3 = seasonal[ph + 3];
            *reinterpret_cast<float4*>(out_seas + base + g) =
                make_float4(s0, s1, s2, s3);
            *reinterpret_cast<float4*>(out_res + base + g) =
                make_float4(resv[j][0] - s0, resv[j][1] - s1,
                            resv[j][2] - s2, resv[j][3] - s3);
        }
        // no row-end barrier: cross-row hazards are ordered by next row's A/B/C
    }
}

extern "C" void kernel_launch(void* const* d_in, const int* in_sizes, int n_in,
                              void* d_out, int out_size, void* d_ws, size_t ws_size,
                              hipStream_t stream) {
    const float* x = (const float*)d_in[0];
    float* out = (float*)d_out;
    const size_t n = (size_t)in_sizes[0];          // 64*128*8192
    const int rows = (int)(n / (size_t)LROW);      // 8192
    const int nblk = rows / RPB;                   // 512
    decomp_kernel<<<nblk, NTHR, 0, stream>>>(x, out, out + n, out + 2 * n);
}